// Round 9
// baseline (111.881 us; speedup 1.0000x reference)
//
#include <hip/hip_runtime.h>

#define NN 256
#define DD 128
#define OC 128
// ws layout: pre[2048][256] f32 = [preA+bm1 (128) | h@Wu_top (128)]  (2 MB)
//            pbB[2048][128] bf16 (packed ushort)                     (512 KB)
//            aiv[2048], ajv[2048] f32

__device__ __forceinline__ float bcastf(float x, int lane) {
    return __int_as_float(__builtin_amdgcn_readlane(__float_as_int(x), lane));
}
__device__ __forceinline__ unsigned short f2bf(float x) {
    unsigned int u = __float_as_uint(x);
    u = (u + 0x7fffu + ((u >> 16) & 1u)) >> 16;   // round-to-nearest-even
    return (unsigned short)u;
}

// ---------------------------------------------------------------------------
// K1: 512 blocks x 4 waves; block = 4 rows. Waves 0-2 each compute one
// 128-col region for all 4 rows (float4 weight loads covering two d-rows:
// lane = (dsel = l>>5, colquad q = l&31); even/odd-d partials combined by
// shfl_xor(32)). Wave 3: ai/aj dots. Regions: 0 = h@Wm1_top + bm1 (f32),
// 1 = h@Wm1_bot -> bf16 pbB, 2 = h@Wu_top (f32). No LDS, no barriers.
// ---------------------------------------------------------------------------
__global__ __launch_bounds__(256, 4) void k1_pre(
    const float* __restrict__ h, const float* __restrict__ Wm1,
    const float* __restrict__ Wa, const float* __restrict__ bm1,
    const float* __restrict__ Wu, const float* __restrict__ ba,
    float* __restrict__ pre, unsigned short* __restrict__ pbB,
    float* __restrict__ aiv, float* __restrict__ ajv)
{
    const int tid  = threadIdx.x;
    const int l    = tid & 63;
    const int w    = tid >> 6;
    const int row0 = blockIdx.x * 4;

    const float2* h2 = (const float2*)h;
    float2 hr[4];
    #pragma unroll
    for (int r = 0; r < 4; ++r) hr[r] = h2[(row0 + r) * 64 + l];

    if (w == 3) {
        const float2* Wa2 = (const float2*)Wa;
        const float2 wt = Wa2[l], wb = Wa2[64 + l];
        float vi[4], vj[4];
        #pragma unroll
        for (int r = 0; r < 4; ++r) {
            vi[r] = hr[r].x * wt.x + hr[r].y * wt.y;
            vj[r] = hr[r].x * wb.x + hr[r].y * wb.y;
        }
        #pragma unroll
        for (int o = 1; o < 64; o <<= 1) {
            #pragma unroll
            for (int r = 0; r < 4; ++r) {
                vi[r] += __shfl_xor(vi[r], o, 64);
                vj[r] += __shfl_xor(vj[r], o, 64);
            }
        }
        if (l == 0) {
            const float b0 = ba[0];
            #pragma unroll
            for (int r = 0; r < 4; ++r) {
                aiv[row0 + r] = vi[r] + b0;
                ajv[row0 + r] = vj[r];
            }
        }
        return;
    }

    const float* Wbase = (w == 0) ? Wm1 : (w == 1) ? (Wm1 + DD * OC) : Wu;
    const float4* W4 = (const float4*)Wbase;
    const int dsel = l >> 5;
    const int q    = l & 31;

    float4 a[4];
    #pragma unroll
    for (int r = 0; r < 4; ++r) a[r] = make_float4(0.f, 0.f, 0.f, 0.f);

    #pragma unroll 8
    for (int i = 0; i < 64; ++i) {
        const float4 wv = W4[(2 * i + dsel) * 32 + q];
        #pragma unroll
        for (int r = 0; r < 4; ++r) {
            const float he = bcastf(hr[r].x, i);
            const float ho = bcastf(hr[r].y, i);
            const float hx = dsel ? ho : he;
            a[r].x = fmaf(hx, wv.x, a[r].x);
            a[r].y = fmaf(hx, wv.y, a[r].y);
            a[r].z = fmaf(hx, wv.z, a[r].z);
            a[r].w = fmaf(hx, wv.w, a[r].w);
        }
    }
    #pragma unroll
    for (int r = 0; r < 4; ++r) {
        a[r].x += __shfl_xor(a[r].x, 32, 64);
        a[r].y += __shfl_xor(a[r].y, 32, 64);
        a[r].z += __shfl_xor(a[r].z, 32, 64);
        a[r].w += __shfl_xor(a[r].w, 32, 64);
    }

    if (l < 32) {
        if (w == 1) {                       // preB -> bf16
            #pragma unroll
            for (int r = 0; r < 4; ++r) {
                ushort4 p;
                p.x = f2bf(a[r].x); p.y = f2bf(a[r].y);
                p.z = f2bf(a[r].z); p.w = f2bf(a[r].w);
                ((ushort4*)pbB)[(row0 + r) * 32 + q] = p;
            }
        } else {
            float4* pre4 = (float4*)pre;    // pre row = 256 f32 = 64 float4
            const int roff = (w == 0) ? 0 : 32;
            if (w == 0) {
                const float4 bb = ((const float4*)bm1)[q];
                #pragma unroll
                for (int r = 0; r < 4; ++r) {
                    a[r].x += bb.x; a[r].y += bb.y;
                    a[r].z += bb.z; a[r].w += bb.w;
                }
            }
            #pragma unroll
            for (int r = 0; r < 4; ++r)
                pre4[(row0 + r) * 64 + roff + q] = a[r];
        }
    }
}

// ---------------------------------------------------------------------------
// K2 (fused): 256 blocks x 16 waves (1024 thr); block = 8 rows x 2 j-halves,
// 1 block/CU. Stage: batch's preB slice (256x128 bf16 = 64 KB) -> LDS once.
// Softmax: wave (r,hf) owns 128 j, lane owns 2 j; butterfly + pair combine.
// Phase B: branch-free weighted relu over the wave's 128 j; preB from LDS
// (uint = 2 bf16 ch per lane, 2-way bank aliasing = free).
// Phases C/D: thread = (row, col); Wm2/Wu read once per 8 rows (L1 serves
// the 8-way row redundancy inside the block).
// ---------------------------------------------------------------------------
__global__ __launch_bounds__(1024, 4) void k2_main(
    const int* __restrict__ adj, const float* __restrict__ dist,
    const float* __restrict__ Wm1, const float* __restrict__ Wa,
    const float* __restrict__ pre, const unsigned short* __restrict__ pbB,
    const float* __restrict__ aiv, const float* __restrict__ ajv,
    const float* __restrict__ Wm2, const float* __restrict__ bm2,
    const float* __restrict__ Wu,  const float* __restrict__ bu,
    float* __restrict__ out)
{
    const int tid  = threadIdx.x;
    const int l    = tid & 63;
    const int wid  = tid >> 6;          // 0..15
    const int r    = wid >> 1;          // row within block (0..7)
    const int hf   = wid & 1;           // j-half
    const int row0 = blockIdx.x * 8;
    const int row  = row0 + r;
    const int b    = row0 >> 8;         // 32 blocks per batch, never straddle

    __shared__ unsigned int pB[NN * 64];    // 64 KB: bf16 preB slice (uint = 2ch)
    __shared__ float mx_sh[16], sm_sh[16], sf_sh[8];
    __shared__ float tp_sh[16][128];        // 8 KB per-wave partial t
    __shared__ float t_sh[8][128];          // 4 KB
    __shared__ float agg_sh[8][128];        // 4 KB

    // ---- stage preB -> LDS (uint4, coalesced; 4096 uint4 / 1024 thr) ----
    {
        const uint4* src = (const uint4*)(pbB + (size_t)b * NN * 128);
        uint4* dst = (uint4*)pB;
        #pragma unroll
        for (int it = 0; it < 4; ++it)
            dst[tid + 1024 * it] = src[tid + 1024 * it];
    }

    // ---- softmax: lane owns j = hf*128 + 2l, 2l+1 ----
    const int2   mk2 = ((const int2*)  (adj  + row * NN))[hf * 64 + l];
    const float2 dv2 = ((const float2*)(dist + row * NN))[hf * 64 + l];
    const float2 aj2 = ((const float2*)(ajv  + b   * NN))[hf * 64 + l];
    const float  ai  = aiv[row];
    const float  dc  = Wa[2 * DD];

    float l0 = ai + aj2.x + dv2.x * dc;
    float l1 = ai + aj2.y + dv2.y * dc;
    l0 = (l0 >= 0.f) ? l0 : 0.2f * l0;
    l1 = (l1 >= 0.f) ? l1 : 0.2f * l1;

    float m = fmaxf(mk2.x ? l0 : -1e9f, mk2.y ? l1 : -1e9f);
    #pragma unroll
    for (int o = 1; o < 64; o <<= 1) m = fmaxf(m, __shfl_xor(m, o, 64));
    if (l == 0) mx_sh[wid] = m;
    __syncthreads();
    const float mx = fmaxf(mx_sh[2 * r], mx_sh[2 * r + 1]);

    const float e0 = mk2.x ? __expf(l0 - mx) : 0.f;
    const float e1 = mk2.y ? __expf(l1 - mx) : 0.f;
    float s = e0 + e1;
    #pragma unroll
    for (int o = 1; o < 64; o <<= 1) s += __shfl_xor(s, o, 64);
    if (l == 0) sm_sh[wid] = s;
    __syncthreads();                    // also guarantees pB staged
    const float esum = sm_sh[2 * r] + sm_sh[2 * r + 1];
    const float inv  = (esum > 0.f) ? (1.0f / esum) : 0.f;
    const float w0 = e0 * inv, w1 = e1 * inv;   // exactly 0 for masked j
    if (l == 0 && hf == 0) sf_sh[r] = (esum > 0.f) ? 1.f : 0.f;

    // ---- phase B: branch-free weighted relu over this wave's 128 j ----
    const float2 pa  = ((const float2*)(pre + row * 256))[l];       // preA+bm1
    const float2 wd1 = ((const float2*)Wm1)[2 * DD * 64 + l];       // d-coef
    const unsigned int* pBh = pB + (hf * 128) * 64;

    float2 acc = {0.f, 0.f};
    #pragma unroll 8
    for (int p = 0; p < 64; ++p) {
        const float w0p = bcastf(w0, p);
        const float d0p = bcastf(dv2.x, p);
        const float w1p = bcastf(w1, p);
        const float d1p = bcastf(dv2.y, p);
        const unsigned int u0 = pBh[(2 * p) * 64 + l];
        const unsigned int u1 = pBh[(2 * p + 1) * 64 + l];
        {
            const float pbx = __uint_as_float(u0 << 16);
            const float pby = __uint_as_float(u0 & 0xffff0000u);
            const float vx = fmaf(d0p, wd1.x, pa.x + pbx);
            const float vy = fmaf(d0p, wd1.y, pa.y + pby);
            acc.x = fmaf(w0p, fmaxf(vx, 0.f), acc.x);
            acc.y = fmaf(w0p, fmaxf(vy, 0.f), acc.y);
        }
        {
            const float pbx = __uint_as_float(u1 << 16);
            const float pby = __uint_as_float(u1 & 0xffff0000u);
            const float vx = fmaf(d1p, wd1.x, pa.x + pbx);
            const float vy = fmaf(d1p, wd1.y, pa.y + pby);
            acc.x = fmaf(w1p, fmaxf(vx, 0.f), acc.x);
            acc.y = fmaf(w1p, fmaxf(vy, 0.f), acc.y);
        }
    }
    tp_sh[wid][2 * l]     = acc.x;
    tp_sh[wid][2 * l + 1] = acc.y;
    __syncthreads();

    // combine the two j-half partials (1024 threads = 8 rows x 128 ch)
    const int rr = tid >> 7, cc = tid & 127;
    t_sh[rr][cc] = tp_sh[2 * rr][cc] + tp_sh[2 * rr + 1][cc];
    __syncthreads();

    // ---- phase C: agg = t @ Wm2 + bm2*sf (thread = (row, col)) ----
    float av = 0.f;
    #pragma unroll 8
    for (int k = 0; k < 128; ++k)
        av = fmaf(t_sh[rr][k], Wm2[k * OC + cc], av);
    agg_sh[rr][cc] = fmaf(bm2[cc], sf_sh[rr], av);
    __syncthreads();

    // ---- phase D: out = relu(hu + agg @ Wu_bot + bu) ----
    float ov = 0.f;
    #pragma unroll 8
    for (int k = 0; k < 128; ++k)
        ov = fmaf(agg_sh[rr][k], Wu[(DD + k) * OC + cc], ov);
    const float hu = pre[(row0 + rr) * 256 + 128 + cc];
    out[(row0 + rr) * OC + cc] = fmaxf(ov + hu + bu[cc], 0.f);
}

extern "C" void kernel_launch(void* const* d_in, const int* in_sizes, int n_in,
                              void* d_out, int out_size, void* d_ws, size_t ws_size,
                              hipStream_t stream) {
    const float* h    = (const float*)d_in[0];
    const int*   adj  = (const int*)  d_in[1];
    const float* dist = (const float*)d_in[2];
    const float* Wm1  = (const float*)d_in[3];
    const float* bm1  = (const float*)d_in[4];
    const float* Wm2  = (const float*)d_in[5];
    const float* bm2  = (const float*)d_in[6];
    const float* Wa   = (const float*)d_in[7];
    const float* ba   = (const float*)d_in[8];
    const float* Wu   = (const float*)d_in[9];
    const float* bu   = (const float*)d_in[10];
    float* out = (float*)d_out;

    float*          pre = (float*)d_ws;                   // 2048*256 f32 = 2 MB
    unsigned short* pbB = (unsigned short*)(pre + 2048 * 256);  // 512 KB
    float*          aiv = (float*)(pbB + 2048 * 128);     // 2048
    float*          ajv = aiv + 2048;                     // 2048

    k1_pre <<<512, 256, 0, stream>>>(h, Wm1, Wa, bm1, Wu, ba, pre, pbB, aiv, ajv);
    k2_main<<<256, 1024, 0, stream>>>(adj, dist, Wm1, Wa, pre, pbB, aiv, ajv,
                                      Wm2, bm2, Wu, bu, out);
}

// Round 10
// 108.619 us; speedup vs baseline: 1.0300x; 1.0300x over previous
//
#include <hip/hip_runtime.h>

#define NN 256
#define DD 128
#define OC 128
// ws layout: pre[2048][256] f32 = [preA+bm1 (128) | h@Wu_top (128)]  (2 MB)
//            pbB[2048][128] bf16 (packed ushort)                     (512 KB)
//            aiv[2048], ajv[2048] f32

__device__ __forceinline__ float bcastf(float x, int lane) {
    return __int_as_float(__builtin_amdgcn_readlane(__float_as_int(x), lane));
}
__device__ __forceinline__ unsigned short f2bf(float x) {
    unsigned int u = __float_as_uint(x);
    u = (u + 0x7fffu + ((u >> 16) & 1u)) >> 16;   // round-to-nearest-even
    return (unsigned short)u;
}

// ---------------------------------------------------------------------------
// K1: 512 blocks x 4 waves; block = 4 rows. Waves 0-2 each compute one
// 128-col region for all 4 rows (float4 weight loads covering two d-rows:
// lane = (dsel = l>>5, colquad q = l&31); even/odd-d partials combined by
// shfl_xor(32)). Wave 3: ai/aj dots. Regions: 0 = h@Wm1_top + bm1 (f32),
// 1 = h@Wm1_bot -> bf16 pbB, 2 = h@Wu_top (f32). No LDS, no barriers.
// ---------------------------------------------------------------------------
__global__ __launch_bounds__(256, 4) void k1_pre(
    const float* __restrict__ h, const float* __restrict__ Wm1,
    const float* __restrict__ Wa, const float* __restrict__ bm1,
    const float* __restrict__ Wu, const float* __restrict__ ba,
    float* __restrict__ pre, unsigned short* __restrict__ pbB,
    float* __restrict__ aiv, float* __restrict__ ajv)
{
    const int tid  = threadIdx.x;
    const int l    = tid & 63;
    const int w    = tid >> 6;
    const int row0 = blockIdx.x * 4;

    const float2* h2 = (const float2*)h;
    float2 hr[4];
    #pragma unroll
    for (int r = 0; r < 4; ++r) hr[r] = h2[(row0 + r) * 64 + l];

    if (w == 3) {
        const float2* Wa2 = (const float2*)Wa;
        const float2 wt = Wa2[l], wb = Wa2[64 + l];
        float vi[4], vj[4];
        #pragma unroll
        for (int r = 0; r < 4; ++r) {
            vi[r] = hr[r].x * wt.x + hr[r].y * wt.y;
            vj[r] = hr[r].x * wb.x + hr[r].y * wb.y;
        }
        #pragma unroll
        for (int o = 1; o < 64; o <<= 1) {
            #pragma unroll
            for (int r = 0; r < 4; ++r) {
                vi[r] += __shfl_xor(vi[r], o, 64);
                vj[r] += __shfl_xor(vj[r], o, 64);
            }
        }
        if (l == 0) {
            const float b0 = ba[0];
            #pragma unroll
            for (int r = 0; r < 4; ++r) {
                aiv[row0 + r] = vi[r] + b0;
                ajv[row0 + r] = vj[r];
            }
        }
        return;
    }

    const float* Wbase = (w == 0) ? Wm1 : (w == 1) ? (Wm1 + DD * OC) : Wu;
    const float4* W4 = (const float4*)Wbase;
    const int dsel = l >> 5;
    const int q    = l & 31;

    float4 a[4];
    #pragma unroll
    for (int r = 0; r < 4; ++r) a[r] = make_float4(0.f, 0.f, 0.f, 0.f);

    #pragma unroll 8
    for (int i = 0; i < 64; ++i) {
        const float4 wv = W4[(2 * i + dsel) * 32 + q];
        #pragma unroll
        for (int r = 0; r < 4; ++r) {
            const float he = bcastf(hr[r].x, i);
            const float ho = bcastf(hr[r].y, i);
            const float hx = dsel ? ho : he;
            a[r].x = fmaf(hx, wv.x, a[r].x);
            a[r].y = fmaf(hx, wv.y, a[r].y);
            a[r].z = fmaf(hx, wv.z, a[r].z);
            a[r].w = fmaf(hx, wv.w, a[r].w);
        }
    }
    #pragma unroll
    for (int r = 0; r < 4; ++r) {
        a[r].x += __shfl_xor(a[r].x, 32, 64);
        a[r].y += __shfl_xor(a[r].y, 32, 64);
        a[r].z += __shfl_xor(a[r].z, 32, 64);
        a[r].w += __shfl_xor(a[r].w, 32, 64);
    }

    if (l < 32) {
        if (w == 1) {                       // preB -> bf16
            #pragma unroll
            for (int r = 0; r < 4; ++r) {
                ushort4 p;
                p.x = f2bf(a[r].x); p.y = f2bf(a[r].y);
                p.z = f2bf(a[r].z); p.w = f2bf(a[r].w);
                ((ushort4*)pbB)[(row0 + r) * 32 + q] = p;
            }
        } else {
            float4* pre4 = (float4*)pre;    // pre row = 256 f32 = 64 float4
            const int roff = (w == 0) ? 0 : 32;
            if (w == 0) {
                const float4 bb = ((const float4*)bm1)[q];
                #pragma unroll
                for (int r = 0; r < 4; ++r) {
                    a[r].x += bb.x; a[r].y += bb.y;
                    a[r].z += bb.z; a[r].w += bb.w;
                }
            }
            #pragma unroll
            for (int r = 0; r < 4; ++r)
                pre4[(row0 + r) * 64 + roff + q] = a[r];
        }
    }
}

// ---------------------------------------------------------------------------
// K2 (fused): 512 blocks x 8 waves (512 thr); block = 4 rows x 2 j-halves.
// Stage: batch's preB slice (256x128 bf16 = 64 KB) -> LDS once.
// Softmax: lane owns 2 j, butterfly + cross-wave pair combine.
// Phase B: branch-free weighted relu over this wave's 128 j; preB from LDS
// (uint per lane = 2 bf16 ch, 2-way bank aliasing = free).
// Phases C/D: thread = (row, col); weights read once per 4 rows.
// ---------------------------------------------------------------------------
__global__ __launch_bounds__(512, 4) void k2_main(
    const int* __restrict__ adj, const float* __restrict__ dist,
    const float* __restrict__ Wm1, const float* __restrict__ Wa,
    const float* __restrict__ pre, const unsigned short* __restrict__ pbB,
    const float* __restrict__ aiv, const float* __restrict__ ajv,
    const float* __restrict__ Wm2, const float* __restrict__ bm2,
    const float* __restrict__ Wu,  const float* __restrict__ bu,
    float* __restrict__ out)
{
    const int tid  = threadIdx.x;
    const int l    = tid & 63;
    const int wid  = tid >> 6;
    const int r    = wid >> 1;          // row within block (0..3)
    const int hf   = wid & 1;           // j-half
    const int row0 = blockIdx.x * 4;
    const int row  = row0 + r;
    const int b    = row0 >> 8;         // 64 blocks per batch, never straddle

    __shared__ unsigned int pB[NN * 64];    // 64 KB: bf16 preB slice (uint = 2ch)
    __shared__ float mx_sh[8], sm_sh[8], sf_sh[4];
    __shared__ float tp_sh[8][128];
    __shared__ float t_sh[4][128];
    __shared__ float agg_sh[4][128];

    // ---- stage preB -> LDS (uint4, coalesced) ----
    {
        const uint4* src = (const uint4*)(pbB + (size_t)b * NN * 128);
        uint4* dst = (uint4*)pB;
        #pragma unroll
        for (int it = 0; it < 8; ++it)
            dst[tid + 512 * it] = src[tid + 512 * it];
    }

    // ---- softmax: lane owns j = hf*128 + 2l, 2l+1 ----
    const int2   mk2 = ((const int2*)  (adj  + row * NN))[hf * 64 + l];
    const float2 dv2 = ((const float2*)(dist + row * NN))[hf * 64 + l];
    const float2 aj2 = ((const float2*)(ajv  + b   * NN))[hf * 64 + l];
    const float  ai  = aiv[row];
    const float  dc  = Wa[2 * DD];

    float l0 = ai + aj2.x + dv2.x * dc;
    float l1 = ai + aj2.y + dv2.y * dc;
    l0 = (l0 >= 0.f) ? l0 : 0.2f * l0;
    l1 = (l1 >= 0.f) ? l1 : 0.2f * l1;

    float m = fmaxf(mk2.x ? l0 : -1e9f, mk2.y ? l1 : -1e9f);
    #pragma unroll
    for (int o = 1; o < 64; o <<= 1) m = fmaxf(m, __shfl_xor(m, o, 64));
    if (l == 0) mx_sh[wid] = m;
    __syncthreads();
    const float mx = fmaxf(mx_sh[2 * r], mx_sh[2 * r + 1]);

    const float e0 = mk2.x ? __expf(l0 - mx) : 0.f;
    const float e1 = mk2.y ? __expf(l1 - mx) : 0.f;
    float s = e0 + e1;
    #pragma unroll
    for (int o = 1; o < 64; o <<= 1) s += __shfl_xor(s, o, 64);
    if (l == 0) sm_sh[wid] = s;
    __syncthreads();                    // also guarantees pB staged
    const float esum = sm_sh[2 * r] + sm_sh[2 * r + 1];
    const float inv  = (esum > 0.f) ? (1.0f / esum) : 0.f;
    const float w0 = e0 * inv, w1 = e1 * inv;   // exactly 0 for masked j
    if (l == 0 && hf == 0) sf_sh[r] = (esum > 0.f) ? 1.f : 0.f;

    // ---- phase B: branch-free weighted relu over this wave's 128 j ----
    const float2 pa  = ((const float2*)(pre + row * 256))[l];       // preA+bm1
    const float2 wd1 = ((const float2*)Wm1)[2 * DD * 64 + l];       // d-coef
    const unsigned int* pBh = pB + (hf * 128) * 64;

    float2 acc = {0.f, 0.f};
    #pragma unroll 8
    for (int p = 0; p < 64; ++p) {
        const float w0p = bcastf(w0, p);
        const float d0p = bcastf(dv2.x, p);
        const float w1p = bcastf(w1, p);
        const float d1p = bcastf(dv2.y, p);
        const unsigned int u0 = pBh[(2 * p) * 64 + l];
        const unsigned int u1 = pBh[(2 * p + 1) * 64 + l];
        {
            const float pbx = __uint_as_float(u0 << 16);
            const float pby = __uint_as_float(u0 & 0xffff0000u);
            const float vx = fmaf(d0p, wd1.x, pa.x + pbx);
            const float vy = fmaf(d0p, wd1.y, pa.y + pby);
            acc.x = fmaf(w0p, fmaxf(vx, 0.f), acc.x);
            acc.y = fmaf(w0p, fmaxf(vy, 0.f), acc.y);
        }
        {
            const float pbx = __uint_as_float(u1 << 16);
            const float pby = __uint_as_float(u1 & 0xffff0000u);
            const float vx = fmaf(d1p, wd1.x, pa.x + pbx);
            const float vy = fmaf(d1p, wd1.y, pa.y + pby);
            acc.x = fmaf(w1p, fmaxf(vx, 0.f), acc.x);
            acc.y = fmaf(w1p, fmaxf(vy, 0.f), acc.y);
        }
    }
    tp_sh[wid][2 * l]     = acc.x;
    tp_sh[wid][2 * l + 1] = acc.y;
    __syncthreads();

    // combine the two j-half partials (512 threads = 4 rows x 128 ch)
    const int rr = tid >> 7, cc = tid & 127;
    t_sh[rr][cc] = tp_sh[2 * rr][cc] + tp_sh[2 * rr + 1][cc];
    __syncthreads();

    // ---- phase C: agg = t @ Wm2 + bm2*sf (thread = (row, col)) ----
    float av = 0.f;
    #pragma unroll 8
    for (int k = 0; k < 128; ++k)
        av = fmaf(t_sh[rr][k], Wm2[k * OC + cc], av);
    agg_sh[rr][cc] = fmaf(bm2[cc], sf_sh[rr], av);
    __syncthreads();

    // ---- phase D: out = relu(hu + agg @ Wu_bot + bu) ----
    float ov = 0.f;
    #pragma unroll 8
    for (int k = 0; k < 128; ++k)
        ov = fmaf(agg_sh[rr][k], Wu[(DD + k) * OC + cc], ov);
    const float hu = pre[(row0 + rr) * 256 + 128 + cc];
    out[(row0 + rr) * OC + cc] = fmaxf(ov + hu + bu[cc], 0.f);
}

extern "C" void kernel_launch(void* const* d_in, const int* in_sizes, int n_in,
                              void* d_out, int out_size, void* d_ws, size_t ws_size,
                              hipStream_t stream) {
    const float* h    = (const float*)d_in[0];
    const int*   adj  = (const int*)  d_in[1];
    const float* dist = (const float*)d_in[2];
    const float* Wm1  = (const float*)d_in[3];
    const float* bm1  = (const float*)d_in[4];
    const float* Wm2  = (const float*)d_in[5];
    const float* bm2  = (const float*)d_in[6];
    const float* Wa   = (const float*)d_in[7];
    const float* ba   = (const float*)d_in[8];
    const float* Wu   = (const float*)d_in[9];
    const float* bu   = (const float*)d_in[10];
    float* out = (float*)d_out;

    float*          pre = (float*)d_ws;                   // 2048*256 f32 = 2 MB
    unsigned short* pbB = (unsigned short*)(pre + 2048 * 256);  // 512 KB
    float*          aiv = (float*)(pbB + 2048 * 128);     // 2048
    float*          ajv = aiv + 2048;                     // 2048

    k1_pre <<<512, 256, 0, stream>>>(h, Wm1, Wa, bm1, Wu, ba, pre, pbB, aiv, ajv);
    k2_main<<<512, 512, 0, stream>>>(adj, dist, Wm1, Wa, pre, pbB, aiv, ajv,
                                     Wm2, bm2, Wu, bu, out);
}